// Round 5
// baseline (558.029 us; speedup 1.0000x reference)
//
#include <hip/hip_runtime.h>
#include <math.h>

// Problem constants (match setup_inputs)
#define B_ROWS 2048
#define N_ANCH 50000
#define DIM    256
#define TOPK   50

// Tiling
#define BTS 128        // feature rows per block, sample GEMM (8 waves x 512 thr)
#define BTL 256        // feature rows per block, append GEMM (16 waves x 1024 thr)
#define AT 256         // anchors per tile
#define KC 32          // k per staged chunk (= one MFMA K)
#define NCHUNK 8       // DIM/KC
#define NCH 16         // anchor chunks (50000/16 = 3125)
#define CHUNK 3125
#define NTILES 13      // ceil(3125/256)
#define NSAMP 4096     // sample anchors per row (tile 0 of each chunk)
#define CAPG 2048      // per-row candidate capacity (overlays the 16KB sims row slice)

// Packed-operand slot counts (one slot = 8 bf16 = 16B, in exact LDS staging order)
#define TSF  (16 * 8 * 512)           // sample feat slots: rb(16) x chunk(8) x slot(512)
#define TSF2 (8 * 8 * 1024)           // append feat slots: rb(8) x chunk(8) x slot(1024)
#define TSA  (NCH * NTILES * 8 * 1024)// anchor slots: tileGlobal(208) x chunk(8) x slot(1024)

typedef __attribute__((ext_vector_type(8))) short bf16x8;           // 8 bf16 in 4 VGPRs
typedef __attribute__((ext_vector_type(8))) unsigned short u16x8;
typedef __attribute__((ext_vector_type(4))) float f32x4;

// LDS layouts (double-buffered pass-split staging)
// sample (BTS=128): B 16KB @0, A 8KB @16K, buf 24KB
#define OFF_A_S 16384
#define BUFB_S  24576
// append (BTL=256): B 16KB @0, A 16KB @16K, buf 32KB
#define OFF_A_L 16384
#define BUFB_L  32768

__device__ __forceinline__ void gl_lds16(const void* g, void* l) {
    // async global->LDS, 16B/lane; LDS dest = uniform base + lane*16
    __builtin_amdgcn_global_load_lds(
        (const __attribute__((address_space(1))) unsigned int*)g,
        (__attribute__((address_space(3))) unsigned int*)l, 16, 0, 0);
}

template<int N>
__device__ __forceinline__ void wait_vmcnt() {
    asm volatile("s_waitcnt vmcnt(%0)" :: "n"(N) : "memory");
}
__device__ __forceinline__ void wait_lgkm0() {
    asm volatile("s_waitcnt lgkmcnt(0)" ::: "memory");
}
// raw barrier fenced at IR level so LDS reads/writes can't be hoisted across
__device__ __forceinline__ void pipe_bar() {
    asm volatile("" ::: "memory");
    __builtin_amdgcn_s_barrier();
    asm volatile("" ::: "memory");
}

__device__ __forceinline__ unsigned short f2bf(float x) {
    unsigned u = __float_as_uint(x);
    u += 0x7FFFu + ((u >> 16) & 1u);             // RNE
    return (unsigned short)(u >> 16);
}

// ordered-uint mapping for float (monotone)
__device__ __forceinline__ unsigned f2ord(float f) {
    unsigned u = __float_as_uint(f);
    return (u & 0x80000000u) ? ~u : (u | 0x80000000u);
}
__device__ __forceinline__ float ord2f(unsigned o) {
    return (o & 0x80000000u) ? __uint_as_float(o & 0x7FFFFFFFu) : __uint_as_float(~o);
}

__device__ __forceinline__ void cvt8(const float4 v0, const float4 v1,
                                     u16x8* H, u16x8* L) {
    float f[8] = {v0.x, v0.y, v0.z, v0.w, v1.x, v1.y, v1.z, v1.w};
    u16x8 h, l;
    #pragma unroll
    for (int j = 0; j < 8; ++j) {
        unsigned short hb = f2bf(f[j]);
        h[j] = hb;
        l[j] = f2bf(f[j] - __uint_as_float((unsigned)hb << 16));
    }
    *H = h; *L = l;
}

// K0a: features -> bf16 hi/lo, BTS=128 pages (sample GEMM staging order).
// Page (rb, c) has 512 slots: slot s = kq*128 + r holds row rb*128+r,
// k-elems [c*32 + kq*8, +8).
__global__ __launch_bounds__(256)
void split_pack_feat(const float* __restrict__ x,
                     unsigned short* __restrict__ hi,
                     unsigned short* __restrict__ lo)
{
    const int S  = blockIdx.x * 256 + threadIdx.x;   // [0, TSF)
    const int s  = S & 511;
    const int c  = (S >> 9) & 7;
    const int rb = S >> 12;
    const int r  = s & 127;
    const int kq = s >> 7;
    const int row = (rb << 7) + r;
    const int k   = (c << 5) + (kq << 3);
    const float4* src = (const float4*)(x + (size_t)row * DIM + k);
    u16x8 H, L;
    cvt8(src[0], src[1], &H, &L);
    *(u16x8*)(hi + (size_t)S * 8) = H;
    *(u16x8*)(lo + (size_t)S * 8) = L;
}

// K0a': features -> bf16 hi/lo, BTL=256 pages (append GEMM staging order).
// Page (rb, c) has 1024 slots: slot s = kq*256 + r holds row rb*256+r,
// k-elems [c*32 + kq*8, +8).
__global__ __launch_bounds__(256)
void split_pack_feat256(const float* __restrict__ x,
                        unsigned short* __restrict__ hi,
                        unsigned short* __restrict__ lo)
{
    const int S  = blockIdx.x * 256 + threadIdx.x;   // [0, TSF2)
    const int s  = S & 1023;
    const int c  = (S >> 10) & 7;
    const int rb = S >> 13;
    const int r  = s & 255;
    const int kq = s >> 8;
    const int row = (rb << 8) + r;
    const int k   = (c << 5) + (kq << 3);
    const float4* src = (const float4*)(x + (size_t)row * DIM + k);
    u16x8 H, L;
    cvt8(src[0], src[1], &H, &L);
    *(u16x8*)(hi + (size_t)S * 8) = H;
    *(u16x8*)(lo + (size_t)S * 8) = L;
}

// K0b: anchors -> bf16 hi/lo, packed in LDS staging order.
// tileGlobal tg = cidx*13 + tile; slot S = (tg*8 + c)*1024 + s, where
// s = kq*256 + (anchor-in-tile): holds anchor cidx*3125 + tile*256 + (s&255)
// (clamped), k-elems [c*32 + (s>>8)*8, +8).
__global__ __launch_bounds__(256)
void split_pack_anc(const float* __restrict__ x,
                    unsigned short* __restrict__ hi,
                    unsigned short* __restrict__ lo)
{
    const int S    = blockIdx.x * 256 + threadIdx.x; // [0, TSA)
    const int s    = S & 1023;
    const int c    = (S >> 10) & 7;
    const int tg   = S >> 13;
    const int cidx = tg / NTILES;
    const int tile = tg - cidx * NTILES;
    int a = cidx * CHUNK + (tile << 8) + (s & 255);
    if (a >= N_ANCH) a = N_ANCH - 1;                 // pad slots; masked in GEMM
    const int k = (c << 5) + ((s >> 8) << 3);
    const float4* src = (const float4*)(x + (size_t)a * DIM + k);
    u16x8 H, L;
    cvt8(src[0], src[1], &H, &L);
    *(u16x8*)(hi + (size_t)S * 8) = H;
    *(u16x8*)(lo + (size_t)S * 8) = L;
}

// ---------------- sample GEMM (BTS=128, 8 waves) ----------------

#define STAGE_LOADS_S 3
__device__ __forceinline__ void stage_tile_s(unsigned char* sb,
                                             const unsigned short* __restrict__ Bsrc,
                                             const unsigned short* __restrict__ Asrc,
                                             int w, int lane)
{
    #pragma unroll
    for (int i = 0; i < 2; ++i) {
        const int t = (w << 1) + i;      // 0..15: B slot block
        gl_lds16(Bsrc + ((size_t)t << 9) + (lane << 3), sb + (t << 10));
    }
    gl_lds16(Asrc + (((w << 6) + lane) << 3), sb + OFF_A_S + (w << 10));
}

__device__ __forceinline__ void compute_tile_s(const unsigned char* sb,
                                               int wm, int wn, int quad, int lx,
                                               f32x4 (&acc)[4][4])
{
    bf16x8 bf[4], af[4];
    #pragma unroll
    for (int tn = 0; tn < 4; ++tn) {
        const int a = (wn << 6) + (tn << 4) + lx;
        bf[tn] = *(const bf16x8*)(sb + (quad << 12) + (a << 4));
    }
    #pragma unroll
    for (int tm = 0; tm < 4; ++tm) {
        const int r = (wm << 6) + (tm << 4) + lx;
        af[tm] = *(const bf16x8*)(sb + OFF_A_S + (quad << 11) + (r << 4));
    }
    #pragma unroll
    for (int tm = 0; tm < 4; ++tm)
        #pragma unroll
        for (int tn = 0; tn < 4; ++tn)
            acc[tm][tn] = __builtin_amdgcn_mfma_f32_16x16x32_bf16(af[tm], bf[tn], acc[tm][tn], 0, 0, 0);
}

// SAMPLE GEMM: pass-split 3-pass bf16 MFMA over tile 0 of each chunk;
// counted-vmcnt double-buffered pipeline; XCD-clustered block swizzle.
// 1-D grid of 256 blocks x 512 thr. (512,4): VGPR cap 128 so acc stays
// in registers ((512,6)'s cap of 85 forced a full spill: VGPR 40, WRITE 2.8GB).
__global__ __launch_bounds__(512, 4)
void knn_sample_gemm(const unsigned short* __restrict__ pfhi,
                     const unsigned short* __restrict__ pflo,
                     const unsigned short* __restrict__ pahi,
                     const unsigned short* __restrict__ palo,
                     float* __restrict__ sims)
{
    __shared__ __align__(16) unsigned char sMem[2 * BUFB_S];

    const int tid  = threadIdx.x;
    const int w    = tid >> 6;
    const int lane = tid & 63;
    const int quad = lane >> 4;
    const int lx   = lane & 15;
    const int wm   = w >> 2;
    const int wn   = w & 3;

    // swizzle: id = ((seq*16 + rb) << 3) | xcd ; cidx = seq*8 + xcd
    const int id   = blockIdx.x;
    const int xcd  = id & 7;
    const int t    = id >> 3;            // 0..31
    const int rb   = t & 15;
    const int cidx = ((t >> 4) << 3) | xcd;
    const int rbase = rb * BTS;
    const int tg    = cidx * NTILES;     // tile 0 of this chunk

    const unsigned short* Fp[3] = {pfhi, pflo, pfhi};
    const unsigned short* Bp[3] = {pahi, pahi, palo};

    auto bsrc = [&](int it) {
        return Bp[it >> 3] + (((size_t)(tg << 3)) + (it & 7)) * 8192;
    };
    auto asrc = [&](int it) {
        return Fp[it >> 3] + (((size_t)(rb << 3)) + (it & 7)) * 4096;
    };

    f32x4 acc[4][4];
    const f32x4 z = {0.f, 0.f, 0.f, 0.f};
    #pragma unroll
    for (int tm = 0; tm < 4; ++tm)
        #pragma unroll
        for (int tn = 0; tn < 4; ++tn) acc[tm][tn] = z;

    stage_tile_s(sMem, bsrc(0), asrc(0), w, lane);
    __syncthreads();                                  // one-time full drain

    int cur = 0;
    for (int it = 0; it < 24; ++it) {
        if (it + 1 < 24) {
            stage_tile_s(sMem + (cur ^ 1) * BUFB_S, bsrc(it + 1), asrc(it + 1), w, lane);
            wait_vmcnt<STAGE_LOADS_S>();              // prev stage landed; new stays in flight
        } else {
            wait_vmcnt<0>();
        }
        pipe_bar();
        compute_tile_s(sMem + cur * BUFB_S, wm, wn, quad, lx, acc);
        wait_lgkm0();                                 // ds_reads retired before overwrite
        pipe_bar();
        cur ^= 1;
    }

    // C/D layout: row = 64wm + 16tm + 4quad + reg, col = 64wn + 16tn + lx
    #pragma unroll
    for (int tm = 0; tm < 4; ++tm)
        #pragma unroll
        for (int tn = 0; tn < 4; ++tn)
            #pragma unroll
            for (int reg = 0; reg < 4; ++reg) {
                int row = rbase + (wm << 6) + (tm << 4) + (quad << 2) + reg;
                int col = (wn << 6) + (tn << 4) + lx;
                sims[(size_t)row * NSAMP + cidx * AT + col] = acc[tm][tn][reg];
            }
}

// BISECT: per row, T = value with count(sample >= T) in [50,64] (=> T <= true 50th);
// appends sample survivors to cand (overlaid on the row's own sims), sets cnt.
__global__ __launch_bounds__(256)
void bisect_thresh(const float* __restrict__ sims,
                   uint2* __restrict__ cand, int* __restrict__ cnt,
                   float* __restrict__ Tarr)
{
    __shared__ float sv[NSAMP];                  // 16 KB
    __shared__ float s_rmin[4], s_rmax[4];
    __shared__ int   s_c, s_ns;

    const int row = blockIdx.x;
    const int tid = threadIdx.x;
    const int lane = tid & 63, w = tid >> 6;
    const unsigned long long below = (lane == 0) ? 0ull : (~0ull >> (64 - lane));

    // load row sims into LDS FIRST (cand overlay safety: all reads precede writes)
    const float4* S4 = (const float4*)(sims + (size_t)row * NSAMP);
    for (int i = tid; i < NSAMP / 4; i += 256) ((float4*)sv)[i] = S4[i];
    __syncthreads();

    float lmin = INFINITY, lmax = -INFINITY;
    for (int e0 = 0; e0 < NSAMP; e0 += 256) {
        float v = sv[e0 + tid];
        lmin = fminf(lmin, v); lmax = fmaxf(lmax, v);
    }
    #pragma unroll
    for (int off = 32; off; off >>= 1) {
        lmin = fminf(lmin, __shfl_down(lmin, off));
        lmax = fmaxf(lmax, __shfl_down(lmax, off));
    }
    if (lane == 0) { s_rmin[w] = lmin; s_rmax[w] = lmax; }
    __syncthreads();
    float lo = fminf(fminf(s_rmin[0], s_rmin[1]), fminf(s_rmin[2], s_rmin[3]));
    float mx = fmaxf(fmaxf(s_rmax[0], s_rmax[1]), fmaxf(s_rmax[2], s_rmax[3]));
    float hi = ord2f(f2ord(mx) + 1);             // count(>= hi) == 0
    int clo = NSAMP;
    for (int it = 0; it < 32 && clo > 64; ++it) {
        float mid = 0.5f * (lo + hi);
        if (tid == 0) s_c = 0;
        __syncthreads();
        int lc = 0;
        for (int e0 = 0; e0 < NSAMP; e0 += 256) lc += (sv[e0 + tid] >= mid);
        #pragma unroll
        for (int off = 32; off; off >>= 1) lc += __shfl_down(lc, off);
        if (lane == 0) atomicAdd(&s_c, lc);
        __syncthreads();
        int c = s_c;
        if (c >= TOPK) { lo = mid; clo = c; } else hi = mid;
        __syncthreads();
    }
    if (tid == 0) { Tarr[row] = lo; s_ns = 0; }
    __syncthreads();

    // append survivors (v >= lo): ballot compaction, anchor = chunk*3125 + a
    for (int e0 = 0; e0 < NSAMP; e0 += 256) {
        int e = e0 + tid;
        float v = sv[e];
        bool pred = (v >= lo);
        unsigned long long mk = __ballot(pred);
        int base = 0;
        if (lane == 0) base = atomicAdd(&s_ns, __popcll(mk));
        base = __shfl(base, 0);
        if (pred) {
            int ofs = base + __popcll(mk & below);
            int anchor = (e >> 8) * CHUNK + (e & 255);
            cand[(size_t)row * CAPG + ofs] = make_uint2(__float_as_uint(v), (unsigned)anchor);
        }
    }
    __syncthreads();
    if (tid == 0) cnt[row] = s_ns;               // direct write: no zero_cnt needed
}

// ---------------- append GEMM (BTL=256, 16 waves) ----------------

#define STAGE_LOADS_L 2
__device__ __forceinline__ void stage_tile_l(unsigned char* sb,
                                             const unsigned short* __restrict__ Bsrc,
                                             const unsigned short* __restrict__ Asrc,
                                             int w, int lane)
{
    gl_lds16(Bsrc + ((size_t)w << 9) + (lane << 3), sb + (w << 10));
    gl_lds16(Asrc + ((size_t)w << 9) + (lane << 3), sb + OFF_A_L + (w << 10));
}

__device__ __forceinline__ void compute_tile_l(const unsigned char* sb,
                                               int wm, int wn, int quad, int lx,
                                               f32x4 (&acc)[4][4])
{
    bf16x8 bf[4], af[4];
    #pragma unroll
    for (int tn = 0; tn < 4; ++tn) {
        const int a = (wn << 6) + (tn << 4) + lx;
        bf[tn] = *(const bf16x8*)(sb + (quad << 12) + (a << 4));
    }
    #pragma unroll
    for (int tm = 0; tm < 4; ++tm) {
        const int r = (wm << 6) + (tm << 4) + lx;
        af[tm] = *(const bf16x8*)(sb + OFF_A_L + (quad << 12) + (r << 4));
    }
    #pragma unroll
    for (int tm = 0; tm < 4; ++tm)
        #pragma unroll
        for (int tn = 0; tn < 4; ++tn)
            acc[tm][tn] = __builtin_amdgcn_mfma_f32_16x16x32_bf16(af[tm], bf[tn], acc[tm][tn], 0, 0, 0);
}

// APPEND: pass-split 3-pass MFMA GEMM, ONE tile per block (tiles 1..12);
// BTL=256 rows/block so B bytes are amortized over 2x rows (128 B/MFMA staged
// vs 192 at BT=128 -- the L2-BW floor was the round-4 limiter); counted-vmcnt
// pipeline; XCD-clustered swizzle: 8 rb-blocks of one (cidx,tile) group share
// one XCD's L2. 1-D grid of 1536 blocks x 1024 thr. (1024,4): VGPR cap 128.
__global__ __launch_bounds__(1024, 4)
void knn_mfma_append(const unsigned short* __restrict__ qfhi,
                     const unsigned short* __restrict__ qflo,
                     const unsigned short* __restrict__ pahi,
                     const unsigned short* __restrict__ palo,
                     const float* __restrict__ Tarr,
                     uint2* __restrict__ cand, int* __restrict__ cnt)
{
    __shared__ __align__(16) unsigned char sMem[2 * BUFB_L];
    __shared__ float s_T[BTL];

    const int tid  = threadIdx.x;
    const int w    = tid >> 6;           // 0..15
    const int lane = tid & 63;
    const int quad = lane >> 4;
    const int lx   = lane & 15;
    const int wm   = w >> 2;             // 0..3
    const int wn   = w & 3;              // 0..3

    // swizzle: id = ((gseq*8 + rb) << 3) | xcd ; group g = gseq*8 + xcd (0..191)
    const int id   = blockIdx.x;
    const int xcd  = id & 7;
    const int t    = id >> 3;            // 0..191
    const int rb   = t & 7;
    const int gseq = t >> 3;             // 0..23
    const int g    = (gseq << 3) | xcd;  // 0..191
    const int cidx = g & 15;
    const int tile = 1 + (g >> 4);       // 1..12
    const int rbase = rb * BTL;

    if (tid < BTL) s_T[tid] = Tarr[rbase + tid];

    const unsigned short* Fp[3] = {qfhi, qflo, qfhi};
    const unsigned short* Bp[3] = {pahi, pahi, palo};

    auto bsrc = [&](int it) {
        return Bp[it >> 3] + (((size_t)((cidx * NTILES + tile) << 3)) + (it & 7)) * 8192;
    };
    auto asrc = [&](int it) {
        return Fp[it >> 3] + (((size_t)(rb << 3)) + (it & 7)) * 8192;
    };

    // prologue: stage (pass 0, chunk 0); full drain also publishes s_T
    stage_tile_l(sMem, bsrc(0), asrc(0), w, lane);
    __syncthreads();

    float thr[4][4];
    #pragma unroll
    for (int tm = 0; tm < 4; ++tm)
        #pragma unroll
        for (int reg = 0; reg < 4; ++reg)
            thr[tm][reg] = s_T[(wm << 6) + (tm << 4) + (quad << 2) + reg];

    f32x4 acc[4][4];
    const f32x4 z = {0.f, 0.f, 0.f, 0.f};
    #pragma unroll
    for (int tm = 0; tm < 4; ++tm)
        #pragma unroll
        for (int tn = 0; tn < 4; ++tn) acc[tm][tn] = z;

    int cur = 0;
    for (int it = 0; it < 24; ++it) {
        if (it + 1 < 24) {
            stage_tile_l(sMem + (cur ^ 1) * BUFB_L, bsrc(it + 1), asrc(it + 1), w, lane);
            wait_vmcnt<STAGE_LOADS_L>();
        } else {
            wait_vmcnt<0>();
        }
        pipe_bar();
        compute_tile_l(sMem + cur * BUFB_L, wm, wn, quad, lx, acc);
        wait_lgkm0();
        pipe_bar();
        cur ^= 1;
    }

    const int abase = cidx * CHUNK + tile * AT;
    const int valid = min(AT, CHUNK - tile * AT);   // tail tile: 53

    // threshold-filtered global append (C/D: row = 64wm+16tm+4quad+reg, col = 64wn+16tn+lx)
    #pragma unroll
    for (int tm = 0; tm < 4; ++tm)
        #pragma unroll
        for (int tn = 0; tn < 4; ++tn)
            #pragma unroll
            for (int reg = 0; reg < 4; ++reg) {
                const float v    = acc[tm][tn][reg];
                const int   aoff = (wn << 6) + (tn << 4) + lx;
                if (aoff < valid && v >= thr[tm][reg]) {
                    const int row = rbase + (wm << 6) + (tm << 4) + (quad << 2) + reg;
                    int slot = atomicAdd(&cnt[row], 1);
                    if (slot < CAPG)
                        cand[(size_t)row * CAPG + slot] =
                            make_uint2(__float_as_uint(v), (unsigned)(abase + aoff));
                }
            }
}

// FINAL: pool = cand[row][0..cnt); bisect to T2 (count in [50,96]); exact lex
// rank-scan of survivors. Fallback full scan if bisection won't tighten.
__global__ __launch_bounds__(256)
void knn_final(const uint2* __restrict__ cand, const int* __restrict__ cnt,
               const int* __restrict__ labels, const int* __restrict__ anchor_label,
               float* __restrict__ out)
{
    __shared__ float pv[CAPG];
    __shared__ int   pi[CAPG];
    __shared__ float fv[128];
    __shared__ int   fi[128];
    __shared__ float s_rmin[4], s_rmax[4];
    __shared__ int   s_c, s_m, s_cm;
    __shared__ float s_sum;

    const int row = blockIdx.x;
    const int tid = threadIdx.x;
    const int lane = tid & 63, w = tid >> 6;
    const unsigned long long below = (lane == 0) ? 0ull : (~0ull >> (64 - lane));

    if (tid == 0) { s_sum = 0.f; s_cm = 0; }

    int ns = cnt[row]; if (ns > CAPG) ns = CAPG;
    for (int e0 = 0; e0 < ns; e0 += 256) {
        int e = e0 + tid;
        if (e < ns) {
            uint2 c = cand[(size_t)row * CAPG + e];
            pv[e] = __uint_as_float(c.x); pi[e] = (int)c.y;
        }
    }
    __syncthreads();
    const int mylab = labels[row];

    // block min/max over pool
    float lmin = INFINITY, lmax = -INFINITY;
    for (int e0 = 0; e0 < ns; e0 += 256) {
        int e = e0 + tid;
        if (e < ns) { float v = pv[e]; lmin = fminf(lmin, v); lmax = fmaxf(lmax, v); }
    }
    #pragma unroll
    for (int off = 32; off; off >>= 1) {
        lmin = fminf(lmin, __shfl_down(lmin, off));
        lmax = fmaxf(lmax, __shfl_down(lmax, off));
    }
    if (lane == 0) { s_rmin[w] = lmin; s_rmax[w] = lmax; }
    __syncthreads();
    float lo = fminf(fminf(s_rmin[0], s_rmin[1]), fminf(s_rmin[2], s_rmin[3]));
    float mx = fmaxf(fmaxf(s_rmax[0], s_rmax[1]), fmaxf(s_rmax[2], s_rmax[3]));
    float hi = ord2f(f2ord(mx) + 1);
    int clo = ns;
    for (int it = 0; it < 32 && clo > 96; ++it) {
        float mid = 0.5f * (lo + hi);
        if (tid == 0) s_c = 0;
        __syncthreads();
        int lc = 0;
        for (int e0 = 0; e0 < ns; e0 += 256) {
            int e = e0 + tid;
            lc += (e < ns && pv[e] >= mid);
        }
        #pragma unroll
        for (int off = 32; off; off >>= 1) lc += __shfl_down(lc, off);
        if (lane == 0) atomicAdd(&s_c, lc);
        __syncthreads();
        int c = s_c;
        if (c >= TOPK) { lo = mid; clo = c; } else hi = mid;
        __syncthreads();
    }

    if (clo <= 96) {
        if (tid == 0) s_m = 0;
        __syncthreads();
        for (int e0 = 0; e0 < ns; e0 += 256) {
            int e = e0 + tid;
            bool pred = (e < ns) && (pv[e] >= lo);
            unsigned long long mk = __ballot(pred);
            int base = 0;
            if (lane == 0) base = atomicAdd(&s_m, __popcll(mk));
            base = __shfl(base, 0);
            if (pred) {
                int ofs = base + __popcll(mk & below);
                fv[ofs] = pv[e]; fi[ofs] = pi[e];
            }
        }
        __syncthreads();
        const int m = s_m;           // == clo, in [50,96]
        if (tid < m) {
            float v = fv[tid]; int id = fi[tid];
            int r = 0;
            for (int q = 0; q < m; ++q) {
                float vq = fv[q];
                r += (vq > v) || (vq == v && fi[q] < id);   // smaller index wins ties
            }
            if (r < TOPK) {
                atomicAdd(&s_sum, v);
                if (anchor_label[id] == mylab) atomicAdd(&s_cm, 1);
            }
        }
    } else {
        // fallback: full exact rank scan (pathological value clustering only)
        for (int e0 = 0; e0 < ns; e0 += 256) {
            int e = e0 + tid;
            if (e < ns) {
                float v = pv[e]; int id = pi[e];
                int r = 0;
                for (int q = 0; q < ns; ++q) {
                    float vq = pv[q];
                    r += (vq > v) || (vq == v && pi[q] < id);
                }
                if (r < TOPK) {
                    atomicAdd(&s_sum, v);
                    if (anchor_label[id] == mylab) atomicAdd(&s_cm, 1);
                }
            }
        }
    }
    __syncthreads();
    if (tid == 0) {
        float mlp = (float)s_cm / (float)TOPK;
        out[row]          = -mlp;                 // loss
        out[B_ROWS + row] = s_sum / (float)TOPK;  // mean_sim
    }
}

extern "C" void kernel_launch(void* const* d_in, const int* in_sizes, int n_in,
                              void* d_out, int out_size, void* d_ws, size_t ws_size,
                              hipStream_t stream)
{
    const float* feat         = (const float*)d_in[0];
    const float* anc          = (const float*)d_in[1];
    const int*   labels       = (const int*)d_in[2];
    // d_in[3] = t_labels (unused)
    const int*   anchor_label = (const int*)d_in[4];
    float* out = (float*)d_out;

    char* ws = (char*)d_ws;
    size_t off = 0;
    unsigned short* pfhi = (unsigned short*)(ws + off); off += (size_t)TSF * 16;   // 1.05 MB
    unsigned short* pflo = (unsigned short*)(ws + off); off += (size_t)TSF * 16;   // 1.05 MB
    unsigned short* qfhi = (unsigned short*)(ws + off); off += (size_t)TSF2 * 16;  // 1.05 MB
    unsigned short* qflo = (unsigned short*)(ws + off); off += (size_t)TSF2 * 16;  // 1.05 MB
    unsigned short* pahi = (unsigned short*)(ws + off); off += (size_t)TSA * 16;   // 27.3 MB
    unsigned short* palo = (unsigned short*)(ws + off); off += (size_t)TSA * 16;   // 27.3 MB
    float* sims = (float*)(ws + off);        off += (size_t)B_ROWS * NSAMP * 4;    // 33.5 MB
    uint2* cand = (uint2*)sims;              // overlay: row r's cand slice inside row r's sims
    int*   cnt  = (int*)(ws + off);          off += (size_t)B_ROWS * 4;
    float* Tarr = (float*)(ws + off);        off += (size_t)B_ROWS * 4;            // ~92.3 MB total

    hipLaunchKernelGGL(split_pack_feat, dim3(TSF / 256), dim3(256), 0, stream,
                       feat, pfhi, pflo);
    hipLaunchKernelGGL(split_pack_feat256, dim3(TSF2 / 256), dim3(256), 0, stream,
                       feat, qfhi, qflo);
    hipLaunchKernelGGL(split_pack_anc, dim3(TSA / 256), dim3(256), 0, stream,
                       anc, pahi, palo);
    hipLaunchKernelGGL(knn_sample_gemm, dim3(256), dim3(512), 0, stream,
                       pfhi, pflo, pahi, palo, sims);            // tile 0 of each chunk
    hipLaunchKernelGGL(bisect_thresh, dim3(B_ROWS), dim3(256), 0, stream,
                       sims, cand, cnt, Tarr);
    hipLaunchKernelGGL(knn_mfma_append, dim3(1536), dim3(1024), 0, stream,
                       qfhi, qflo, pahi, palo, Tarr, cand, cnt); // tiles 1..12
    hipLaunchKernelGGL(knn_final, dim3(B_ROWS), dim3(256), 0, stream,
                       cand, cnt, labels, anchor_label, out);
}

// Round 7
// 526.736 us; speedup vs baseline: 1.0594x; 1.0594x over previous
//
#include <hip/hip_runtime.h>
#include <math.h>

// Problem constants (match setup_inputs)
#define B_ROWS 2048
#define N_ANCH 50000
#define DIM    256
#define TOPK   50

// Tiling
#define BT 128         // feature rows per block (8 waves)
#define AT 256         // anchors per tile
#define KC 32          // k per staged chunk (= one MFMA K)
#define NCHUNK 8       // DIM/KC
#define NCH 16         // anchor chunks (50000/16 = 3125)
#define CHUNK 3125
#define NTILES 13      // ceil(3125/256)
#define NSAMP 4096     // sample anchors per row (tile 0 of each chunk)
#define CAPG 2048      // per-row candidate capacity (overlays the 16KB sims row slice)

// Packed-operand slot counts (one slot = 8 bf16 = 16B, in exact LDS staging order)
#define NRB (B_ROWS / BT)             // 16 feature row-blocks
#define TSF (NRB * 8 * 512)           // feature slots: rb(16) x chunk(8) x slot(512)
#define TSA (NCH * NTILES * 8 * 1024) // anchor slots: tileGlobal(208) x chunk(8) x slot(1024)

typedef __attribute__((ext_vector_type(8))) short bf16x8;           // 8 bf16 in 4 VGPRs
typedef __attribute__((ext_vector_type(8))) unsigned short u16x8;
typedef __attribute__((ext_vector_type(4))) float f32x4;

// LDS layout: ring-of-3 pass-split staging (3 x 24 KB)
#define OFF_B 0            // anchors: slot = kq*256 + a, 16B/slot -> 16 KB
#define OFF_A 16384        // feats:   slot = kq*128 + r, 16B/slot -> 8 KB
#define BUFB  24576
#define SMEM_BYTES (3 * BUFB)

__device__ __forceinline__ void gl_lds16(const void* g, void* l) {
    // async global->LDS, 16B/lane; LDS dest = uniform base + lane*16
    __builtin_amdgcn_global_load_lds(
        (const __attribute__((address_space(1))) unsigned int*)g,
        (__attribute__((address_space(3))) unsigned int*)l, 16, 0, 0);
}

template<int N>
__device__ __forceinline__ void wait_vmcnt() {
    asm volatile("s_waitcnt vmcnt(%0)" :: "n"(N) : "memory");
}
__device__ __forceinline__ void wait_lgkm0() {
    asm volatile("s_waitcnt lgkmcnt(0)" ::: "memory");
}
// raw barrier fenced at IR level so LDS reads/writes can't be hoisted across
__device__ __forceinline__ void pipe_bar() {
    asm volatile("" ::: "memory");
    __builtin_amdgcn_s_barrier();
    asm volatile("" ::: "memory");
}

__device__ __forceinline__ unsigned short f2bf(float x) {
    unsigned u = __float_as_uint(x);
    u += 0x7FFFu + ((u >> 16) & 1u);             // RNE
    return (unsigned short)(u >> 16);
}

// ordered-uint mapping for float (monotone)
__device__ __forceinline__ unsigned f2ord(float f) {
    unsigned u = __float_as_uint(f);
    return (u & 0x80000000u) ? ~u : (u | 0x80000000u);
}
__device__ __forceinline__ float ord2f(unsigned o) {
    return (o & 0x80000000u) ? __uint_as_float(o & 0x7FFFFFFFu) : __uint_as_float(~o);
}

__device__ __forceinline__ void cvt8(const float4 v0, const float4 v1,
                                     u16x8* H, u16x8* L) {
    float f[8] = {v0.x, v0.y, v0.z, v0.w, v1.x, v1.y, v1.z, v1.w};
    u16x8 h, l;
    #pragma unroll
    for (int j = 0; j < 8; ++j) {
        unsigned short hb = f2bf(f[j]);
        h[j] = hb;
        l[j] = f2bf(f[j] - __uint_as_float((unsigned)hb << 16));
    }
    *H = h; *L = l;
}

// K0a: split fp32 features -> bf16 hi/lo, packed in LDS staging order.
// Page (rb, c) has 512 slots: slot s = kq*128 + r holds row rb*128+r,
// k-elems [c*32 + kq*8, +8).
__global__ __launch_bounds__(256)
void split_pack_feat(const float* __restrict__ x,
                     unsigned short* __restrict__ hi,
                     unsigned short* __restrict__ lo)
{
    const int S  = blockIdx.x * 256 + threadIdx.x;   // [0, TSF)
    const int s  = S & 511;
    const int c  = (S >> 9) & 7;
    const int rb = S >> 12;
    const int r  = s & 127;
    const int kq = s >> 7;
    const int row = (rb << 7) + r;
    const int k   = (c << 5) + (kq << 3);
    const float4* src = (const float4*)(x + (size_t)row * DIM + k);
    u16x8 H, L;
    cvt8(src[0], src[1], &H, &L);
    *(u16x8*)(hi + (size_t)S * 8) = H;
    *(u16x8*)(lo + (size_t)S * 8) = L;
}

// K0b: split fp32 anchors -> bf16 hi/lo, packed in LDS staging order.
// tileGlobal tg = cidx*13 + tile; slot S = (tg*8 + c)*1024 + s, where
// s = kq*256 + (anchor-in-tile): holds anchor cidx*3125 + tile*256 + (s&255)
// (clamped), k-elems [c*32 + (s>>8)*8, +8).
__global__ __launch_bounds__(256)
void split_pack_anc(const float* __restrict__ x,
                    unsigned short* __restrict__ hi,
                    unsigned short* __restrict__ lo)
{
    const int S    = blockIdx.x * 256 + threadIdx.x; // [0, TSA)
    const int s    = S & 1023;
    const int c    = (S >> 10) & 7;
    const int tg   = S >> 13;
    const int cidx = tg / NTILES;
    const int tile = tg - cidx * NTILES;
    int a = cidx * CHUNK + (tile << 8) + (s & 255);
    if (a >= N_ANCH) a = N_ANCH - 1;                 // pad slots; masked in GEMM
    const int k = (c << 5) + ((s >> 8) << 3);
    const float4* src = (const float4*)(x + (size_t)a * DIM + k);
    u16x8 H, L;
    cvt8(src[0], src[1], &H, &L);
    *(u16x8*)(hi + (size_t)S * 8) = H;
    *(u16x8*)(lo + (size_t)S * 8) = L;
}

// Stage one (pass, chunk) operand set into LDS buffer sb (8 waves, 3 loads/wave).
// All loads are fully coalesced 1KB wave loads from packed layout.
#define STAGE_LOADS 3
__device__ __forceinline__ void stage_tile(unsigned char* sb,
                                           const unsigned short* __restrict__ Bsrc,
                                           const unsigned short* __restrict__ Asrc,
                                           int w, int lane)
{
    #pragma unroll
    for (int i = 0; i < 2; ++i) {
        const int t = (w << 1) + i;      // 0..15: B slot block
        gl_lds16(Bsrc + ((size_t)t << 9) + (lane << 3), sb + OFF_B + (t << 10));
    }
    gl_lds16(Asrc + (((w << 6) + lane) << 3), sb + OFF_A + (w << 10));
}

// 8-wave compute: wave (wm = w>>2, wn = w&3) owns rows [wm*64,+64) x cols [wn*64,+64)
__device__ __forceinline__ void compute_tile(const unsigned char* sb,
                                             int wm, int wn, int quad, int lx,
                                             f32x4 (&acc)[4][4])
{
    bf16x8 bf[4], af[4];
    #pragma unroll
    for (int tn = 0; tn < 4; ++tn) {
        const int a = (wn << 6) + (tn << 4) + lx;
        bf[tn] = *(const bf16x8*)(sb + OFF_B + (quad << 12) + (a << 4));
    }
    #pragma unroll
    for (int tm = 0; tm < 4; ++tm) {
        const int r = (wm << 6) + (tm << 4) + lx;
        af[tm] = *(const bf16x8*)(sb + OFF_A + (quad << 11) + (r << 4));
    }
    __builtin_amdgcn_s_setprio(1);
    #pragma unroll
    for (int tm = 0; tm < 4; ++tm)
        #pragma unroll
        for (int tn = 0; tn < 4; ++tn)
            acc[tm][tn] = __builtin_amdgcn_mfma_f32_16x16x32_bf16(af[tm], bf[tn], acc[tm][tn], 0, 0, 0);
    __builtin_amdgcn_s_setprio(0);
}

// Ring-of-3 K-loop body, shared by both GEMMs. Per phase it (one barrier):
//   stage(it+2) -> buf[(it+2)%3]  (== buffer read at it-1; WAR fenced by the
//                                  barrier that ended phase it-1)
//   compute(it) from buf[it%3]    (loads landed: prev phase's vmcnt(3) drained
//                                  them before the shared barrier)
//   lgkm0                          (my ds_reads retired before others overwrite)
//   vmcnt(3)                       (keep newest stage; phase it+1's loads landed)
//   s_barrier
// Loads get ~2 full phases to land; numerics identical to the 2-barrier loop.

// SAMPLE GEMM: pass-split 3-pass bf16 MFMA over tile 0 of each chunk;
// ring-of-3 counted-vmcnt pipeline; XCD-clustered block swizzle.
// 1-D grid of 256 blocks x 512 thr. (512,4): VGPR cap 128 so acc stays in
// registers ((512,6)'s cap of 85 forced a full spill: VGPR 40, WRITE 2.8GB).
__global__ __launch_bounds__(512, 4)
void knn_sample_gemm(const unsigned short* __restrict__ pfhi,
                     const unsigned short* __restrict__ pflo,
                     const unsigned short* __restrict__ pahi,
                     const unsigned short* __restrict__ palo,
                     float* __restrict__ sims)
{
    __shared__ __align__(16) unsigned char sMem[SMEM_BYTES];

    const int tid  = threadIdx.x;
    const int w    = tid >> 6;
    const int lane = tid & 63;
    const int quad = lane >> 4;
    const int lx   = lane & 15;
    const int wm   = w >> 2;
    const int wn   = w & 3;

    // swizzle: id = ((seq*16 + rb) << 3) | xcd ; cidx = seq*8 + xcd
    const int id   = blockIdx.x;
    const int xcd  = id & 7;
    const int t    = id >> 3;            // 0..31
    const int rb   = t & 15;
    const int cidx = ((t >> 4) << 3) | xcd;
    const int rbase = rb * BT;
    const int tg    = cidx * NTILES;     // tile 0 of this chunk

    const unsigned short* Fp[3] = {pfhi, pflo, pfhi};
    const unsigned short* Bp[3] = {pahi, pahi, palo};

    auto bsrc = [&](int it) {
        return Bp[it >> 3] + (((size_t)(tg << 3)) + (it & 7)) * 8192;
    };
    auto asrc = [&](int it) {
        return Fp[it >> 3] + (((size_t)(rb << 3)) + (it & 7)) * 4096;
    };

    f32x4 acc[4][4];
    const f32x4 z = {0.f, 0.f, 0.f, 0.f};
    #pragma unroll
    for (int tm = 0; tm < 4; ++tm)
        #pragma unroll
        for (int tn = 0; tn < 4; ++tn) acc[tm][tn] = z;

    // prologue: stage phases 0 and 1; full drain (simple, once per kernel)
    stage_tile(sMem + 0 * BUFB, bsrc(0), asrc(0), w, lane);
    stage_tile(sMem + 1 * BUFB, bsrc(1), asrc(1), w, lane);
    __syncthreads();

    for (int it = 0; it < 24; ++it) {
        if (it + 2 < 24)
            stage_tile(sMem + ((it + 2) % 3) * BUFB, bsrc(it + 2), asrc(it + 2), w, lane);
        compute_tile(sMem + (it % 3) * BUFB, wm, wn, quad, lx, acc);
        wait_lgkm0();
        if (it + 2 < 24)      wait_vmcnt<STAGE_LOADS>();
        else if (it + 1 < 24) wait_vmcnt<0>();
        pipe_bar();
    }

    // C/D layout: row = 64wm + 16tm + 4quad + reg, col = 64wn + 16tn + lx
    #pragma unroll
    for (int tm = 0; tm < 4; ++tm)
        #pragma unroll
        for (int tn = 0; tn < 4; ++tn)
            #pragma unroll
            for (int reg = 0; reg < 4; ++reg) {
                int row = rbase + (wm << 6) + (tm << 4) + (quad << 2) + reg;
                int col = (wn << 6) + (tn << 4) + lx;
                sims[(size_t)row * NSAMP + cidx * AT + col] = acc[tm][tn][reg];
            }
}

// BISECT: per row, T = value with count(sample >= T) in [50,64] (=> T <= true 50th);
// appends sample survivors to cand (overlaid on the row's own sims), sets cnt.
__global__ __launch_bounds__(256)
void bisect_thresh(const float* __restrict__ sims,
                   uint2* __restrict__ cand, int* __restrict__ cnt,
                   float* __restrict__ Tarr)
{
    __shared__ float sv[NSAMP];                  // 16 KB
    __shared__ float s_rmin[4], s_rmax[4];
    __shared__ int   s_c, s_ns;

    const int row = blockIdx.x;
    const int tid = threadIdx.x;
    const int lane = tid & 63, w = tid >> 6;
    const unsigned long long below = (lane == 0) ? 0ull : (~0ull >> (64 - lane));

    // load row sims into LDS FIRST (cand overlay safety: all reads precede writes)
    const float4* S4 = (const float4*)(sims + (size_t)row * NSAMP);
    for (int i = tid; i < NSAMP / 4; i += 256) ((float4*)sv)[i] = S4[i];
    __syncthreads();

    float lmin = INFINITY, lmax = -INFINITY;
    for (int e0 = 0; e0 < NSAMP; e0 += 256) {
        float v = sv[e0 + tid];
        lmin = fminf(lmin, v); lmax = fmaxf(lmax, v);
    }
    #pragma unroll
    for (int off = 32; off; off >>= 1) {
        lmin = fminf(lmin, __shfl_down(lmin, off));
        lmax = fmaxf(lmax, __shfl_down(lmax, off));
    }
    if (lane == 0) { s_rmin[w] = lmin; s_rmax[w] = lmax; }
    __syncthreads();
    float lo = fminf(fminf(s_rmin[0], s_rmin[1]), fminf(s_rmin[2], s_rmin[3]));
    float mx = fmaxf(fmaxf(s_rmax[0], s_rmax[1]), fmaxf(s_rmax[2], s_rmax[3]));
    float hi = ord2f(f2ord(mx) + 1);             // count(>= hi) == 0
    int clo = NSAMP;
    for (int it = 0; it < 32 && clo > 64; ++it) {
        float mid = 0.5f * (lo + hi);
        if (tid == 0) s_c = 0;
        __syncthreads();
        int lc = 0;
        for (int e0 = 0; e0 < NSAMP; e0 += 256) lc += (sv[e0 + tid] >= mid);
        #pragma unroll
        for (int off = 32; off; off >>= 1) lc += __shfl_down(lc, off);
        if (lane == 0) atomicAdd(&s_c, lc);
        __syncthreads();
        int c = s_c;
        if (c >= TOPK) { lo = mid; clo = c; } else hi = mid;
        __syncthreads();
    }
    if (tid == 0) { Tarr[row] = lo; s_ns = 0; }
    __syncthreads();

    // append survivors (v >= lo): ballot compaction, anchor = chunk*3125 + a
    for (int e0 = 0; e0 < NSAMP; e0 += 256) {
        int e = e0 + tid;
        float v = sv[e];
        bool pred = (v >= lo);
        unsigned long long mk = __ballot(pred);
        int base = 0;
        if (lane == 0) base = atomicAdd(&s_ns, __popcll(mk));
        base = __shfl(base, 0);
        if (pred) {
            int ofs = base + __popcll(mk & below);
            int anchor = (e >> 8) * CHUNK + (e & 255);
            cand[(size_t)row * CAPG + ofs] = make_uint2(__float_as_uint(v), (unsigned)anchor);
        }
    }
    __syncthreads();
    if (tid == 0) cnt[row] = s_ns;               // direct write: no zero_cnt needed
}

// APPEND: pass-split 3-pass MFMA GEMM, ONE tile per block (tiles 1..12);
// ring-of-3 counted-vmcnt pipeline (one barrier/phase, loads span 2 phases);
// XCD-clustered swizzle: 16 rb-blocks of one (cidx,tile) group share one
// XCD's L2. 1-D grid of 3072 blocks x 512 thr. (512,4): VGPR cap 128.
__global__ __launch_bounds__(512, 4)
void knn_mfma_append(const unsigned short* __restrict__ pfhi,
                     const unsigned short* __restrict__ pflo,
                     const unsigned short* __restrict__ pahi,
                     const unsigned short* __restrict__ palo,
                     const float* __restrict__ Tarr,
                     uint2* __restrict__ cand, int* __restrict__ cnt)
{
    __shared__ __align__(16) unsigned char sMem[SMEM_BYTES];
    __shared__ float s_T[BT];

    const int tid  = threadIdx.x;
    const int w    = tid >> 6;
    const int lane = tid & 63;
    const int quad = lane >> 4;
    const int lx   = lane & 15;
    const int wm   = w >> 2;
    const int wn   = w & 3;

    // swizzle: id = ((gseq*16 + rb) << 3) | xcd ; group g = gseq*8 + xcd (0..191)
    const int id   = blockIdx.x;
    const int xcd  = id & 7;
    const int t    = id >> 3;            // 0..383
    const int rb   = t & 15;
    const int gseq = t >> 4;             // 0..23
    const int g    = (gseq << 3) | xcd;  // 0..191
    const int cidx = g & 15;
    const int tile = 1 + (g >> 4);       // 1..12
    const int rbase = rb * BT;

    if (tid < BT) s_T[tid] = Tarr[rbase + tid];

    // prologue: stage phases 0 and 1; full drain also publishes s_T
    const unsigned short* Fp[3] = {pfhi, pflo, pfhi};
    const unsigned short* Bp[3] = {pahi, pahi, palo};

    auto bsrc = [&](int it) {
        return Bp[it >> 3] + (((size_t)((cidx * NTILES + tile) << 3)) + (it & 7)) * 8192;
    };
    auto asrc = [&](int it) {
        return Fp[it >> 3] + (((size_t)(rb << 3)) + (it & 7)) * 4096;
    };

    stage_tile(sMem + 0 * BUFB, bsrc(0), asrc(0), w, lane);
    stage_tile(sMem + 1 * BUFB, bsrc(1), asrc(1), w, lane);
    __syncthreads();

    float thr[4][4];
    #pragma unroll
    for (int tm = 0; tm < 4; ++tm)
        #pragma unroll
        for (int reg = 0; reg < 4; ++reg)
            thr[tm][reg] = s_T[(wm << 6) + (tm << 4) + (quad << 2) + reg];

    f32x4 acc[4][4];
    const f32x4 z = {0.f, 0.f, 0.f, 0.f};
    #pragma unroll
    for (int tm = 0; tm < 4; ++tm)
        #pragma unroll
        for (int tn = 0; tn < 4; ++tn) acc[tm][tn] = z;

    for (int it = 0; it < 24; ++it) {
        if (it + 2 < 24)
            stage_tile(sMem + ((it + 2) % 3) * BUFB, bsrc(it + 2), asrc(it + 2), w, lane);
        compute_tile(sMem + (it % 3) * BUFB, wm, wn, quad, lx, acc);
        wait_lgkm0();
        if (it + 2 < 24)      wait_vmcnt<STAGE_LOADS>();
        else if (it + 1 < 24) wait_vmcnt<0>();
        pipe_bar();
    }

    const int abase = cidx * CHUNK + tile * AT;
    const int valid = min(AT, CHUNK - tile * AT);   // tail tile: 53

    // threshold-filtered global append (C/D: row = 64wm+16tm+4quad+reg, col = 64wn+16tn+lx)
    #pragma unroll
    for (int tm = 0; tm < 4; ++tm)
        #pragma unroll
        for (int tn = 0; tn < 4; ++tn)
            #pragma unroll
            for (int reg = 0; reg < 4; ++reg) {
                const float v    = acc[tm][tn][reg];
                const int   aoff = (wn << 6) + (tn << 4) + lx;
                if (aoff < valid && v >= thr[tm][reg]) {
                    const int row = rbase + (wm << 6) + (tm << 4) + (quad << 2) + reg;
                    int slot = atomicAdd(&cnt[row], 1);
                    if (slot < CAPG)
                        cand[(size_t)row * CAPG + slot] =
                            make_uint2(__float_as_uint(v), (unsigned)(abase + aoff));
                }
            }
}

// FINAL: pool = cand[row][0..cnt); bisect to T2 (count in [50,96]); exact lex
// rank-scan of survivors. Fallback full scan if bisection won't tighten.
__global__ __launch_bounds__(256)
void knn_final(const uint2* __restrict__ cand, const int* __restrict__ cnt,
               const int* __restrict__ labels, const int* __restrict__ anchor_label,
               float* __restrict__ out)
{
    __shared__ float pv[CAPG];
    __shared__ int   pi[CAPG];
    __shared__ float fv[128];
    __shared__ int   fi[128];
    __shared__ float s_rmin[4], s_rmax[4];
    __shared__ int   s_c, s_m, s_cm;
    __shared__ float s_sum;

    const int row = blockIdx.x;
    const int tid = threadIdx.x;
    const int lane = tid & 63, w = tid >> 6;
    const unsigned long long below = (lane == 0) ? 0ull : (~0ull >> (64 - lane));

    if (tid == 0) { s_sum = 0.f; s_cm = 0; }

    int ns = cnt[row]; if (ns > CAPG) ns = CAPG;
    for (int e0 = 0; e0 < ns; e0 += 256) {
        int e = e0 + tid;
        if (e < ns) {
            uint2 c = cand[(size_t)row * CAPG + e];
            pv[e] = __uint_as_float(c.x); pi[e] = (int)c.y;
        }
    }
    __syncthreads();
    const int mylab = labels[row];

    // block min/max over pool
    float lmin = INFINITY, lmax = -INFINITY;
    for (int e0 = 0; e0 < ns; e0 += 256) {
        int e = e0 + tid;
        if (e < ns) { float v = pv[e]; lmin = fminf(lmin, v); lmax = fmaxf(lmax, v); }
    }
    #pragma unroll
    for (int off = 32; off; off >>= 1) {
        lmin = fminf(lmin, __shfl_down(lmin, off));
        lmax = fmaxf(lmax, __shfl_down(lmax, off));
    }
    if (lane == 0) { s_rmin[w] = lmin; s_rmax[w] = lmax; }
    __syncthreads();
    float lo = fminf(fminf(s_rmin[0], s_rmin[1]), fminf(s_rmin[2], s_rmin[3]));
    float mx = fmaxf(fmaxf(s_rmax[0], s_rmax[1]), fmaxf(s_rmax[2], s_rmax[3]));
    float hi = ord2f(f2ord(mx) + 1);
    int clo = ns;
    for (int it = 0; it < 32 && clo > 96; ++it) {
        float mid = 0.5f * (lo + hi);
        if (tid == 0) s_c = 0;
        __syncthreads();
        int lc = 0;
        for (int e0 = 0; e0 < ns; e0 += 256) {
            int e = e0 + tid;
            lc += (e < ns && pv[e] >= mid);
        }
        #pragma unroll
        for (int off = 32; off; off >>= 1) lc += __shfl_down(lc, off);
        if (lane == 0) atomicAdd(&s_c, lc);
        __syncthreads();
        int c = s_c;
        if (c >= TOPK) { lo = mid; clo = c; } else hi = mid;
        __syncthreads();
    }

    if (clo <= 96) {
        if (tid == 0) s_m = 0;
        __syncthreads();
        for (int e0 = 0; e0 < ns; e0 += 256) {
            int e = e0 + tid;
            bool pred = (e < ns) && (pv[e] >= lo);
            unsigned long long mk = __ballot(pred);
            int base = 0;
            if (lane == 0) base = atomicAdd(&s_m, __popcll(mk));
            base = __shfl(base, 0);
            if (pred) {
                int ofs = base + __popcll(mk & below);
                fv[ofs] = pv[e]; fi[ofs] = pi[e];
            }
        }
        __syncthreads();
        const int m = s_m;           // == clo, in [50,96]
        if (tid < m) {
            float v = fv[tid]; int id = fi[tid];
            int r = 0;
            for (int q = 0; q < m; ++q) {
                float vq = fv[q];
                r += (vq > v) || (vq == v && fi[q] < id);   // smaller index wins ties
            }
            if (r < TOPK) {
                atomicAdd(&s_sum, v);
                if (anchor_label[id] == mylab) atomicAdd(&s_cm, 1);
            }
        }
    } else {
        // fallback: full exact rank scan (pathological value clustering only)
        for (int e0 = 0; e0 < ns; e0 += 256) {
            int e = e0 + tid;
            if (e < ns) {
                float v = pv[e]; int id = pi[e];
                int r = 0;
                for (int q = 0; q < ns; ++q) {
                    float vq = pv[q];
                    r += (vq > v) || (vq == v && pi[q] < id);
                }
                if (r < TOPK) {
                    atomicAdd(&s_sum, v);
                    if (anchor_label[id] == mylab) atomicAdd(&s_cm, 1);
                }
            }
        }
    }
    __syncthreads();
    if (tid == 0) {
        float mlp = (float)s_cm / (float)TOPK;
        out[row]          = -mlp;                 // loss
        out[B_ROWS + row] = s_sum / (float)TOPK;  // mean_sim
    }
}

extern "C" void kernel_launch(void* const* d_in, const int* in_sizes, int n_in,
                              void* d_out, int out_size, void* d_ws, size_t ws_size,
                              hipStream_t stream)
{
    const float* feat         = (const float*)d_in[0];
    const float* anc          = (const float*)d_in[1];
    const int*   labels       = (const int*)d_in[2];
    // d_in[3] = t_labels (unused)
    const int*   anchor_label = (const int*)d_in[4];
    float* out = (float*)d_out;

    char* ws = (char*)d_ws;
    size_t off = 0;
    unsigned short* pfhi = (unsigned short*)(ws + off); off += (size_t)TSF * 16;   // 1.05 MB
    unsigned short* pflo = (unsigned short*)(ws + off); off += (size_t)TSF * 16;   // 1.05 MB
    unsigned short* pahi = (unsigned short*)(ws + off); off += (size_t)TSA * 16;   // 27.3 MB
    unsigned short* palo = (unsigned short*)(ws + off); off += (size_t)TSA * 16;   // 27.3 MB
    float* sims = (float*)(ws + off);        off += (size_t)B_ROWS * NSAMP * 4;    // 33.5 MB
    uint2* cand = (uint2*)sims;              // overlay: row r's cand slice inside row r's sims
    int*   cnt  = (int*)(ws + off);          off += (size_t)B_ROWS * 4;
    float* Tarr = (float*)(ws + off);        off += (size_t)B_ROWS * 4;            // ~90.2 MB total

    hipLaunchKernelGGL(split_pack_feat, dim3(TSF / 256), dim3(256), 0, stream,
                       feat, pfhi, pflo);
    hipLaunchKernelGGL(split_pack_anc, dim3(TSA / 256), dim3(256), 0, stream,
                       anc, pahi, palo);
    hipLaunchKernelGGL(knn_sample_gemm, dim3(256), dim3(512), 0, stream,
                       pfhi, pflo, pahi, palo, sims);            // tile 0 of each chunk
    hipLaunchKernelGGL(bisect_thresh, dim3(B_ROWS), dim3(256), 0, stream,
                       sims, cand, cnt, Tarr);
    hipLaunchKernelGGL(knn_mfma_append, dim3(3072), dim3(512), 0, stream,
                       pfhi, pflo, pahi, palo, Tarr, cand, cnt); // tiles 1..12
    hipLaunchKernelGGL(knn_final, dim3(B_ROWS), dim3(256), 0, stream,
                       cand, cnt, labels, anchor_label, out);
}

// Round 8
// 526.110 us; speedup vs baseline: 1.0607x; 1.0012x over previous
//
#include <hip/hip_runtime.h>
#include <math.h>

// Problem constants (match setup_inputs)
#define B_ROWS 2048
#define N_ANCH 50000
#define DIM    256
#define TOPK   50

// Tiling
#define BTS 128        // feature rows per block, sample GEMM (8 waves x 512 thr)
#define BTL 256        // feature rows per block, append GEMM (16 waves x 1024 thr)
#define AT 256         // anchors per tile
#define KC 32          // k per staged chunk (= one MFMA K)
#define NCHUNK 8       // DIM/KC
#define NCH 16         // anchor chunks (50000/16 = 3125)
#define CHUNK 3125
#define NTILES 13      // ceil(3125/256)
#define NSAMP 4096     // sample anchors per row (tile 0 of each chunk)
#define CAPG 2048      // per-row candidate capacity (overlays the 16KB sims row slice)

// Packed-operand slot counts (one slot = 8 bf16 = 16B, in exact LDS staging order)
#define TSF  (16 * 8 * 512)           // sample feat slots: rb(16) x chunk(8) x slot(512)
#define TSF2 (8 * 8 * 1024)           // append feat slots: rb(8) x chunk(8) x slot(1024)
#define TSA  (NCH * NTILES * 8 * 1024)// anchor slots: tileGlobal(208) x chunk(8) x slot(1024)

typedef __attribute__((ext_vector_type(8))) short bf16x8;           // 8 bf16 in 4 VGPRs
typedef __attribute__((ext_vector_type(8))) unsigned short u16x8;
typedef __attribute__((ext_vector_type(4))) float f32x4;

// ---- sample GEMM LDS (ring-of-3, pass-split, 24 KB bufs) ----
#define OFF_B 0
#define OFF_A 16384
#define BUFB  24576
#define SMEM_S (3 * BUFB)

// ---- append GEMM LDS (double-buffer, pass-FUSED, 64 KB bufs) ----
#define OFF_BH 0            // B hi: slot = kq*256 + a  (16 KB)
#define OFF_BL 16384        // B lo                      (16 KB)
#define OFF_AH 32768        // A hi: slot = kq*256 + r  (16 KB)
#define OFF_AL 49152        // A lo                      (16 KB)
#define BUFF   65536

__device__ __forceinline__ void gl_lds16(const void* g, void* l) {
    // async global->LDS, 16B/lane; LDS dest = uniform base + lane*16
    __builtin_amdgcn_global_load_lds(
        (const __attribute__((address_space(1))) unsigned int*)g,
        (__attribute__((address_space(3))) unsigned int*)l, 16, 0, 0);
}

template<int N>
__device__ __forceinline__ void wait_vmcnt() {
    asm volatile("s_waitcnt vmcnt(%0)" :: "n"(N) : "memory");
}
__device__ __forceinline__ void wait_lgkm0() {
    asm volatile("s_waitcnt lgkmcnt(0)" ::: "memory");
}
// raw barrier fenced at IR level so LDS reads/writes can't be hoisted across
__device__ __forceinline__ void pipe_bar() {
    asm volatile("" ::: "memory");
    __builtin_amdgcn_s_barrier();
    asm volatile("" ::: "memory");
}

__device__ __forceinline__ unsigned short f2bf(float x) {
    unsigned u = __float_as_uint(x);
    u += 0x7FFFu + ((u >> 16) & 1u);             // RNE
    return (unsigned short)(u >> 16);
}

// ordered-uint mapping for float (monotone)
__device__ __forceinline__ unsigned f2ord(float f) {
    unsigned u = __float_as_uint(f);
    return (u & 0x80000000u) ? ~u : (u | 0x80000000u);
}
__device__ __forceinline__ float ord2f(unsigned o) {
    return (o & 0x80000000u) ? __uint_as_float(o & 0x7FFFFFFFu) : __uint_as_float(~o);
}

__device__ __forceinline__ void cvt8(const float4 v0, const float4 v1,
                                     u16x8* H, u16x8* L) {
    float f[8] = {v0.x, v0.y, v0.z, v0.w, v1.x, v1.y, v1.z, v1.w};
    u16x8 h, l;
    #pragma unroll
    for (int j = 0; j < 8; ++j) {
        unsigned short hb = f2bf(f[j]);
        h[j] = hb;
        l[j] = f2bf(f[j] - __uint_as_float((unsigned)hb << 16));
    }
    *H = h; *L = l;
}

// K0a: features -> bf16 hi/lo, BTS=128 pages (sample GEMM staging order).
// Page (rb, c) has 512 slots: slot s = kq*128 + r holds row rb*128+r,
// k-elems [c*32 + kq*8, +8).
__global__ __launch_bounds__(256)
void split_pack_feat(const float* __restrict__ x,
                     unsigned short* __restrict__ hi,
                     unsigned short* __restrict__ lo)
{
    const int S  = blockIdx.x * 256 + threadIdx.x;   // [0, TSF)
    const int s  = S & 511;
    const int c  = (S >> 9) & 7;
    const int rb = S >> 12;
    const int r  = s & 127;
    const int kq = s >> 7;
    const int row = (rb << 7) + r;
    const int k   = (c << 5) + (kq << 3);
    const float4* src = (const float4*)(x + (size_t)row * DIM + k);
    u16x8 H, L;
    cvt8(src[0], src[1], &H, &L);
    *(u16x8*)(hi + (size_t)S * 8) = H;
    *(u16x8*)(lo + (size_t)S * 8) = L;
}

// K0a': features -> bf16 hi/lo, BTL=256 pages (append GEMM staging order).
// Page (rb, c) has 1024 slots: slot s = kq*256 + r holds row rb*256+r,
// k-elems [c*32 + kq*8, +8).
__global__ __launch_bounds__(256)
void split_pack_feat256(const float* __restrict__ x,
                        unsigned short* __restrict__ hi,
                        unsigned short* __restrict__ lo)
{
    const int S  = blockIdx.x * 256 + threadIdx.x;   // [0, TSF2)
    const int s  = S & 1023;
    const int c  = (S >> 10) & 7;
    const int rb = S >> 13;
    const int r  = s & 255;
    const int kq = s >> 8;
    const int row = (rb << 8) + r;
    const int k   = (c << 5) + (kq << 3);
    const float4* src = (const float4*)(x + (size_t)row * DIM + k);
    u16x8 H, L;
    cvt8(src[0], src[1], &H, &L);
    *(u16x8*)(hi + (size_t)S * 8) = H;
    *(u16x8*)(lo + (size_t)S * 8) = L;
}

// K0b: anchors -> bf16 hi/lo, packed in LDS staging order.
// tileGlobal tg = cidx*13 + tile; slot S = (tg*8 + c)*1024 + s, where
// s = kq*256 + (anchor-in-tile): holds anchor cidx*3125 + tile*256 + (s&255)
// (clamped), k-elems [c*32 + (s>>8)*8, +8).
__global__ __launch_bounds__(256)
void split_pack_anc(const float* __restrict__ x,
                    unsigned short* __restrict__ hi,
                    unsigned short* __restrict__ lo)
{
    const int S    = blockIdx.x * 256 + threadIdx.x; // [0, TSA)
    const int s    = S & 1023;
    const int c    = (S >> 10) & 7;
    const int tg   = S >> 13;
    const int cidx = tg / NTILES;
    const int tile = tg - cidx * NTILES;
    int a = cidx * CHUNK + (tile << 8) + (s & 255);
    if (a >= N_ANCH) a = N_ANCH - 1;                 // pad slots; masked in GEMM
    const int k = (c << 5) + ((s >> 8) << 3);
    const float4* src = (const float4*)(x + (size_t)a * DIM + k);
    u16x8 H, L;
    cvt8(src[0], src[1], &H, &L);
    *(u16x8*)(hi + (size_t)S * 8) = H;
    *(u16x8*)(lo + (size_t)S * 8) = L;
}

// ---------------- sample GEMM (BTS=128, 8 waves, ring-of-3, pass-split) ----------------

#define STAGE_LOADS 3
__device__ __forceinline__ void stage_tile(unsigned char* sb,
                                           const unsigned short* __restrict__ Bsrc,
                                           const unsigned short* __restrict__ Asrc,
                                           int w, int lane)
{
    #pragma unroll
    for (int i = 0; i < 2; ++i) {
        const int t = (w << 1) + i;      // 0..15: B slot block
        gl_lds16(Bsrc + ((size_t)t << 9) + (lane << 3), sb + OFF_B + (t << 10));
    }
    gl_lds16(Asrc + (((w << 6) + lane) << 3), sb + OFF_A + (w << 10));
}

__device__ __forceinline__ void compute_tile(const unsigned char* sb,
                                             int wm, int wn, int quad, int lx,
                                             f32x4 (&acc)[4][4])
{
    bf16x8 bf[4], af[4];
    #pragma unroll
    for (int tn = 0; tn < 4; ++tn) {
        const int a = (wn << 6) + (tn << 4) + lx;
        bf[tn] = *(const bf16x8*)(sb + OFF_B + (quad << 12) + (a << 4));
    }
    #pragma unroll
    for (int tm = 0; tm < 4; ++tm) {
        const int r = (wm << 6) + (tm << 4) + lx;
        af[tm] = *(const bf16x8*)(sb + OFF_A + (quad << 11) + (r << 4));
    }
    __builtin_amdgcn_s_setprio(1);
    #pragma unroll
    for (int tm = 0; tm < 4; ++tm)
        #pragma unroll
        for (int tn = 0; tn < 4; ++tn)
            acc[tm][tn] = __builtin_amdgcn_mfma_f32_16x16x32_bf16(af[tm], bf[tn], acc[tm][tn], 0, 0, 0);
    __builtin_amdgcn_s_setprio(0);
}

// SAMPLE GEMM: unchanged from the verified round-7 kernel.
__global__ __launch_bounds__(512, 4)
void knn_sample_gemm(const unsigned short* __restrict__ pfhi,
                     const unsigned short* __restrict__ pflo,
                     const unsigned short* __restrict__ pahi,
                     const unsigned short* __restrict__ palo,
                     float* __restrict__ sims)
{
    __shared__ __align__(16) unsigned char sMem[SMEM_S];

    const int tid  = threadIdx.x;
    const int w    = tid >> 6;
    const int lane = tid & 63;
    const int quad = lane >> 4;
    const int lx   = lane & 15;
    const int wm   = w >> 2;
    const int wn   = w & 3;

    // swizzle: id = ((seq*16 + rb) << 3) | xcd ; cidx = seq*8 + xcd
    const int id   = blockIdx.x;
    const int xcd  = id & 7;
    const int t    = id >> 3;            // 0..31
    const int rb   = t & 15;
    const int cidx = ((t >> 4) << 3) | xcd;
    const int rbase = rb * BTS;
    const int tg    = cidx * NTILES;     // tile 0 of this chunk

    const unsigned short* Fp[3] = {pfhi, pflo, pfhi};
    const unsigned short* Bp[3] = {pahi, pahi, palo};

    auto bsrc = [&](int it) {
        return Bp[it >> 3] + (((size_t)(tg << 3)) + (it & 7)) * 8192;
    };
    auto asrc = [&](int it) {
        return Fp[it >> 3] + (((size_t)(rb << 3)) + (it & 7)) * 4096;
    };

    f32x4 acc[4][4];
    const f32x4 z = {0.f, 0.f, 0.f, 0.f};
    #pragma unroll
    for (int tm = 0; tm < 4; ++tm)
        #pragma unroll
        for (int tn = 0; tn < 4; ++tn) acc[tm][tn] = z;

    stage_tile(sMem + 0 * BUFB, bsrc(0), asrc(0), w, lane);
    stage_tile(sMem + 1 * BUFB, bsrc(1), asrc(1), w, lane);
    __syncthreads();

    for (int it = 0; it < 24; ++it) {
        if (it + 2 < 24)
            stage_tile(sMem + ((it + 2) % 3) * BUFB, bsrc(it + 2), asrc(it + 2), w, lane);
        compute_tile(sMem + (it % 3) * BUFB, wm, wn, quad, lx, acc);
        wait_lgkm0();
        if (it + 2 < 24)      wait_vmcnt<STAGE_LOADS>();
        else if (it + 1 < 24) wait_vmcnt<0>();
        pipe_bar();
    }

    // C/D layout: row = 64wm + 16tm + 4quad + reg, col = 64wn + 16tn + lx
    #pragma unroll
    for (int tm = 0; tm < 4; ++tm)
        #pragma unroll
        for (int tn = 0; tn < 4; ++tn)
            #pragma unroll
            for (int reg = 0; reg < 4; ++reg) {
                int row = rbase + (wm << 6) + (tm << 4) + (quad << 2) + reg;
                int col = (wn << 6) + (tn << 4) + lx;
                sims[(size_t)row * NSAMP + cidx * AT + col] = acc[tm][tn][reg];
            }
}

// BISECT: per row, T = value with count(sample >= T) in [50,64] (=> T <= true 50th);
// appends sample survivors to cand (overlaid on the row's own sims), sets cnt.
__global__ __launch_bounds__(256)
void bisect_thresh(const float* __restrict__ sims,
                   uint2* __restrict__ cand, int* __restrict__ cnt,
                   float* __restrict__ Tarr)
{
    __shared__ float sv[NSAMP];                  // 16 KB
    __shared__ float s_rmin[4], s_rmax[4];
    __shared__ int   s_c, s_ns;

    const int row = blockIdx.x;
    const int tid = threadIdx.x;
    const int lane = tid & 63, w = tid >> 6;
    const unsigned long long below = (lane == 0) ? 0ull : (~0ull >> (64 - lane));

    // load row sims into LDS FIRST (cand overlay safety: all reads precede writes)
    const float4* S4 = (const float4*)(sims + (size_t)row * NSAMP);
    for (int i = tid; i < NSAMP / 4; i += 256) ((float4*)sv)[i] = S4[i];
    __syncthreads();

    float lmin = INFINITY, lmax = -INFINITY;
    for (int e0 = 0; e0 < NSAMP; e0 += 256) {
        float v = sv[e0 + tid];
        lmin = fminf(lmin, v); lmax = fmaxf(lmax, v);
    }
    #pragma unroll
    for (int off = 32; off; off >>= 1) {
        lmin = fminf(lmin, __shfl_down(lmin, off));
        lmax = fmaxf(lmax, __shfl_down(lmax, off));
    }
    if (lane == 0) { s_rmin[w] = lmin; s_rmax[w] = lmax; }
    __syncthreads();
    float lo = fminf(fminf(s_rmin[0], s_rmin[1]), fminf(s_rmin[2], s_rmin[3]));
    float mx = fmaxf(fmaxf(s_rmax[0], s_rmax[1]), fmaxf(s_rmax[2], s_rmax[3]));
    float hi = ord2f(f2ord(mx) + 1);             // count(>= hi) == 0
    int clo = NSAMP;
    for (int it = 0; it < 32 && clo > 64; ++it) {
        float mid = 0.5f * (lo + hi);
        if (tid == 0) s_c = 0;
        __syncthreads();
        int lc = 0;
        for (int e0 = 0; e0 < NSAMP; e0 += 256) lc += (sv[e0 + tid] >= mid);
        #pragma unroll
        for (int off = 32; off; off >>= 1) lc += __shfl_down(lc, off);
        if (lane == 0) atomicAdd(&s_c, lc);
        __syncthreads();
        int c = s_c;
        if (c >= TOPK) { lo = mid; clo = c; } else hi = mid;
        __syncthreads();
    }
    if (tid == 0) { Tarr[row] = lo; s_ns = 0; }
    __syncthreads();

    // append survivors (v >= lo): ballot compaction, anchor = chunk*3125 + a
    for (int e0 = 0; e0 < NSAMP; e0 += 256) {
        int e = e0 + tid;
        float v = sv[e];
        bool pred = (v >= lo);
        unsigned long long mk = __ballot(pred);
        int base = 0;
        if (lane == 0) base = atomicAdd(&s_ns, __popcll(mk));
        base = __shfl(base, 0);
        if (pred) {
            int ofs = base + __popcll(mk & below);
            int anchor = (e >> 8) * CHUNK + (e & 255);
            cand[(size_t)row * CAPG + ofs] = make_uint2(__float_as_uint(v), (unsigned)anchor);
        }
    }
    __syncthreads();
    if (tid == 0) cnt[row] = s_ns;               // direct write: no zero_cnt needed
}

// ---------------- append GEMM (BTL=256, 16 waves, pass-FUSED) ----------------
// Fused staging: {A_hi, A_lo, B_hi, B_lo} for one k-chunk staged ONCE (64 KB);
// all 3 passes (hi.hi, lo.hi, hi.lo) run on it -> 48 MFMA/wave/phase, 8 phases
// total (vs 24), 1.5x fewer staged bytes, no runtime-indexed pointer arrays.

#define STAGE_LOADS_F 4
__device__ __forceinline__ void stage_fused(unsigned char* sb,
                                            const unsigned short* __restrict__ Bh,
                                            const unsigned short* __restrict__ Bl,
                                            const unsigned short* __restrict__ Ah,
                                            const unsigned short* __restrict__ Al,
                                            int w, int lane)
{
    const int o = ((w << 6) + lane) << 3;            // slot * 8 shorts
    gl_lds16(Bh + o, sb + OFF_BH + (w << 10));
    gl_lds16(Bl + o, sb + OFF_BL + (w << 10));
    gl_lds16(Ah + o, sb + OFF_AH + (w << 10));
    gl_lds16(Al + o, sb + OFF_AL + (w << 10));
}

__device__ __forceinline__ void compute_fused(const unsigned char* sb,
                                              int wm, int wn, int quad, int lx,
                                              f32x4 (&acc)[4][4])
{
    bf16x8 afh[4], bfh[4], afl[4], bfl[4];
    #pragma unroll
    for (int tn = 0; tn < 4; ++tn) {
        const int a = (wn << 6) + (tn << 4) + lx;
        bfh[tn] = *(const bf16x8*)(sb + OFF_BH + (quad << 12) + (a << 4));
    }
    #pragma unroll
    for (int tm = 0; tm < 4; ++tm) {
        const int r = (wm << 6) + (tm << 4) + lx;
        afh[tm] = *(const bf16x8*)(sb + OFF_AH + (quad << 12) + (r << 4));
    }
    __builtin_amdgcn_s_setprio(1);
    #pragma unroll
    for (int tm = 0; tm < 4; ++tm)
        #pragma unroll
        for (int tn = 0; tn < 4; ++tn)
            acc[tm][tn] = __builtin_amdgcn_mfma_f32_16x16x32_bf16(afh[tm], bfh[tn], acc[tm][tn], 0, 0, 0);
    __builtin_amdgcn_s_setprio(0);

    #pragma unroll
    for (int tm = 0; tm < 4; ++tm) {
        const int r = (wm << 6) + (tm << 4) + lx;
        afl[tm] = *(const bf16x8*)(sb + OFF_AL + (quad << 12) + (r << 4));
    }
    __builtin_amdgcn_s_setprio(1);
    #pragma unroll
    for (int tm = 0; tm < 4; ++tm)
        #pragma unroll
        for (int tn = 0; tn < 4; ++tn)
            acc[tm][tn] = __builtin_amdgcn_mfma_f32_16x16x32_bf16(afl[tm], bfh[tn], acc[tm][tn], 0, 0, 0);
    __builtin_amdgcn_s_setprio(0);

    #pragma unroll
    for (int tn = 0; tn < 4; ++tn) {
        const int a = (wn << 6) + (tn << 4) + lx;
        bfl[tn] = *(const bf16x8*)(sb + OFF_BL + (quad << 12) + (a << 4));
    }
    __builtin_amdgcn_s_setprio(1);
    #pragma unroll
    for (int tm = 0; tm < 4; ++tm)
        #pragma unroll
        for (int tn = 0; tn < 4; ++tn)
            acc[tm][tn] = __builtin_amdgcn_mfma_f32_16x16x32_bf16(afh[tm], bfl[tn], acc[tm][tn], 0, 0, 0);
    __builtin_amdgcn_s_setprio(0);
}

// APPEND: pass-fused MFMA GEMM, ONE (cidx,tile) per block, BTL=256 rows;
// double-buffered counted-vmcnt (R4's verified scheme), 8 phases/block;
// XCD-clustered swizzle: 8 rb-blocks of one group share one XCD's L2.
// 1-D grid of 1536 blocks x 1024 thr; 128 KB LDS -> 1 block/CU (16 waves, 50%).
__global__ __launch_bounds__(1024, 4)
void knn_mfma_append(const unsigned short* __restrict__ qfhi,
                     const unsigned short* __restrict__ qflo,
                     const unsigned short* __restrict__ pahi,
                     const unsigned short* __restrict__ palo,
                     const float* __restrict__ Tarr,
                     uint2* __restrict__ cand, int* __restrict__ cnt)
{
    __shared__ __align__(16) unsigned char sMem[2 * BUFF];
    __shared__ float s_T[BTL];

    const int tid  = threadIdx.x;
    const int w    = tid >> 6;           // 0..15
    const int lane = tid & 63;
    const int quad = lane >> 4;
    const int lx   = lane & 15;
    const int wm   = w >> 2;             // 0..3
    const int wn   = w & 3;              // 0..3

    // swizzle: id = ((gseq*8 + rb) << 3) | xcd ; group g = gseq*8 + xcd (0..191)
    const int id   = blockIdx.x;
    const int xcd  = id & 7;
    const int t    = id >> 3;            // 0..191
    const int rb   = t & 7;
    const int gseq = t >> 3;             // 0..23
    const int g    = (gseq << 3) | xcd;  // 0..191
    const int cidx = g & 15;
    const int tile = 1 + (g >> 4);       // 1..12
    const int rbase = rb * BTL;

    if (tid < BTL) s_T[tid] = Tarr[rbase + tid];

    const unsigned short* Bh0 = pahi + ((size_t)(cidx * NTILES + tile) << 3) * 8192;
    const unsigned short* Bl0 = palo + ((size_t)(cidx * NTILES + tile) << 3) * 8192;
    const unsigned short* Ah0 = qfhi + ((size_t)rb << 3) * 8192;
    const unsigned short* Al0 = qflo + ((size_t)rb << 3) * 8192;

    f32x4 acc[4][4];
    const f32x4 z = {0.f, 0.f, 0.f, 0.f};
    #pragma unroll
    for (int tm = 0; tm < 4; ++tm)
        #pragma unroll
        for (int tn = 0; tn < 4; ++tn) acc[tm][tn] = z;

    // prologue: stage chunk 0; full drain also publishes s_T
    stage_fused(sMem, Bh0, Bl0, Ah0, Al0, w, lane);
    __syncthreads();

    for (int c = 0; c < NCHUNK; ++c) {
        if (c + 1 < NCHUNK) {
            stage_fused(sMem + ((c + 1) & 1) * BUFF,
                        Bh0 + (size_t)(c + 1) * 8192, Bl0 + (size_t)(c + 1) * 8192,
                        Ah0 + (size_t)(c + 1) * 8192, Al0 + (size_t)(c + 1) * 8192,
                        w, lane);
            wait_vmcnt<STAGE_LOADS_F>();   // drains chunk c's loads; c+1 stays in flight
        } else {
            wait_vmcnt<0>();
        }
        pipe_bar();
        compute_fused(sMem + (c & 1) * BUFF, wm, wn, quad, lx, acc);
        wait_lgkm0();                      // ds_reads retired before buffer overwrite
        pipe_bar();
    }

    // epilogue: thresholds loaded here (not before the loop) to cap VGPR live range
    float thr[4][4];
    #pragma unroll
    for (int tm = 0; tm < 4; ++tm)
        #pragma unroll
        for (int reg = 0; reg < 4; ++reg)
            thr[tm][reg] = s_T[(wm << 6) + (tm << 4) + (quad << 2) + reg];

    const int abase = cidx * CHUNK + tile * AT;
    const int valid = min(AT, CHUNK - tile * AT);   // tail tile: 53

    // threshold-filtered global append (C/D: row = 64wm+16tm+4quad+reg, col = 64wn+16tn+lx)
    #pragma unroll
    for (int tm = 0; tm < 4; ++tm)
        #pragma unroll
        for (int tn = 0; tn < 4; ++tn)
            #pragma unroll
            for (int reg = 0; reg < 4; ++reg) {
                const float v    = acc[tm][tn][reg];
                const int   aoff = (wn << 6) + (tn << 4) + lx;
                if (aoff < valid && v >= thr[tm][reg]) {
                    const int row = rbase + (wm << 6) + (tm << 4) + (quad << 2) + reg;
                    int slot = atomicAdd(&cnt[row], 1);
                    if (slot < CAPG)
                        cand[(size_t)row * CAPG + slot] =
                            make_uint2(__float_as_uint(v), (unsigned)(abase + aoff));
                }
            }
}

// FINAL: pool = cand[row][0..cnt); bisect to T2 (count in [50,96]); exact lex
// rank-scan of survivors. Fallback full scan if bisection won't tighten.
__global__ __launch_bounds__(256)
void knn_final(const uint2* __restrict__ cand, const int* __restrict__ cnt,
               const int* __restrict__ labels, const int* __restrict__ anchor_label,
               float* __restrict__ out)
{
    __shared__ float pv[CAPG];
    __shared__ int   pi[CAPG];
    __shared__ float fv[128];
    __shared__ int   fi[128];
    __shared__ float s_rmin[4], s_rmax[4];
    __shared__ int   s_c, s_m, s_cm;
    __shared__ float s_sum;

    const int row = blockIdx.x;
    const int tid = threadIdx.x;
    const int lane = tid & 63, w = tid >> 6;
    const unsigned long long below = (lane == 0) ? 0ull : (~0ull >> (64 - lane));

    if (tid == 0) { s_sum = 0.f; s_cm = 0; }

    int ns = cnt[row]; if (ns > CAPG) ns = CAPG;
    for (int e0 = 0; e0 < ns; e0 += 256) {
        int e = e0 + tid;
        if (e < ns) {
            uint2 c = cand[(size_t)row * CAPG + e];
            pv[e] = __uint_as_float(c.x); pi[e] = (int)c.y;
        }
    }
    __syncthreads();
    const int mylab = labels[row];

    // block min/max over pool
    float lmin = INFINITY, lmax = -INFINITY;
    for (int e0 = 0; e0 < ns; e0 += 256) {
        int e = e0 + tid;
        if (e < ns) { float v = pv[e]; lmin = fminf(lmin, v); lmax = fmaxf(lmax, v); }
    }
    #pragma unroll
    for (int off = 32; off; off >>= 1) {
        lmin = fminf(lmin, __shfl_down(lmin, off));
        lmax = fmaxf(lmax, __shfl_down(lmax, off));
    }
    if (lane == 0) { s_rmin[w] = lmin; s_rmax[w] = lmax; }
    __syncthreads();
    float lo = fminf(fminf(s_rmin[0], s_rmin[1]), fminf(s_rmin[2], s_rmin[3]));
    float mx = fmaxf(fmaxf(s_rmax[0], s_rmax[1]), fmaxf(s_rmax[2], s_rmax[3]));
    float hi = ord2f(f2ord(mx) + 1);
    int clo = ns;
    for (int it = 0; it < 32 && clo > 96; ++it) {
        float mid = 0.5f * (lo + hi);
        if (tid == 0) s_c = 0;
        __syncthreads();
        int lc = 0;
        for (int e0 = 0; e0 < ns; e0 += 256) {
            int e = e0 + tid;
            lc += (e < ns && pv[e] >= mid);
        }
        #pragma unroll
        for (int off = 32; off; off >>= 1) lc += __shfl_down(lc, off);
        if (lane == 0) atomicAdd(&s_c, lc);
        __syncthreads();
        int c = s_c;
        if (c >= TOPK) { lo = mid; clo = c; } else hi = mid;
        __syncthreads();
    }

    if (clo <= 96) {
        if (tid == 0) s_m = 0;
        __syncthreads();
        for (int e0 = 0; e0 < ns; e0 += 256) {
            int e = e0 + tid;
            bool pred = (e < ns) && (pv[e] >= lo);
            unsigned long long mk = __ballot(pred);
            int base = 0;
            if (lane == 0) base = atomicAdd(&s_m, __popcll(mk));
            base = __shfl(base, 0);
            if (pred) {
                int ofs = base + __popcll(mk & below);
                fv[ofs] = pv[e]; fi[ofs] = pi[e];
            }
        }
        __syncthreads();
        const int m = s_m;           // == clo, in [50,96]
        if (tid < m) {
            float v = fv[tid]; int id = fi[tid];
            int r = 0;
            for (int q = 0; q < m; ++q) {
                float vq = fv[q];
                r += (vq > v) || (vq == v && fi[q] < id);   // smaller index wins ties
            }
            if (r < TOPK) {
                atomicAdd(&s_sum, v);
                if (anchor_label[id] == mylab) atomicAdd(&s_cm, 1);
            }
        }
    } else {
        // fallback: full exact rank scan (pathological value clustering only)
        for (int e0 = 0; e0 < ns; e0 += 256) {
            int e = e0 + tid;
            if (e < ns) {
                float v = pv[e]; int id = pi[e];
                int r = 0;
                for (int q = 0; q < ns; ++q) {
                    float vq = pv[q];
                    r += (vq > v) || (vq == v && pi[q] < id);
                }
                if (r < TOPK) {
                    atomicAdd(&s_sum, v);
                    if (anchor_label[id] == mylab) atomicAdd(&s_cm, 1);
                }
            }
        }
    }
    __syncthreads();
    if (tid == 0) {
        float mlp = (float)s_cm / (float)TOPK;
        out[row]          = -mlp;                 // loss
        out[B_ROWS + row] = s_sum / (float)TOPK;  // mean_sim
    }
}

extern "C" void kernel_launch(void* const* d_in, const int* in_sizes, int n_in,
                              void* d_out, int out_size, void* d_ws, size_t ws_size,
                              hipStream_t stream)
{
    const float* feat         = (const float*)d_in[0];
    const float* anc          = (const float*)d_in[1];
    const int*   labels       = (const int*)d_in[2];
    // d_in[3] = t_labels (unused)
    const int*   anchor_label = (const int*)d_in[4];
    float* out = (float*)d_out;

    char* ws = (char*)d_ws;
    size_t off = 0;
    unsigned short* pfhi = (unsigned short*)(ws + off); off += (size_t)TSF * 16;   // 1.05 MB
    unsigned short* pflo = (unsigned short*)(ws + off); off += (size_t)TSF * 16;   // 1.05 MB
    unsigned short* qfhi = (unsigned short*)(ws + off); off += (size_t)TSF2 * 16;  // 1.05 MB
    unsigned short* qflo = (unsigned short*)(ws + off); off += (size_t)TSF2 * 16;  // 1.05 MB
    unsigned short* pahi = (unsigned short*)(ws + off); off += (size_t)TSA * 16;   // 27.3 MB
    unsigned short* palo = (unsigned short*)(ws + off); off += (size_t)TSA * 16;   // 27.3 MB
    float* sims = (float*)(ws + off);        off += (size_t)B_ROWS * NSAMP * 4;    // 33.5 MB
    uint2* cand = (uint2*)sims;              // overlay: row r's cand slice inside row r's sims
    int*   cnt  = (int*)(ws + off);          off += (size_t)B_ROWS * 4;
    float* Tarr = (float*)(ws + off);        off += (size_t)B_ROWS * 4;            // ~92.3 MB total

    hipLaunchKernelGGL(split_pack_feat, dim3(TSF / 256), dim3(256), 0, stream,
                       feat, pfhi, pflo);
    hipLaunchKernelGGL(split_pack_feat256, dim3(TSF2 / 256), dim3(256), 0, stream,
                       feat, qfhi, qflo);
    hipLaunchKernelGGL(split_pack_anc, dim3(TSA / 256), dim3(256), 0, stream,
                       anc, pahi, palo);
    hipLaunchKernelGGL(knn_sample_gemm, dim3(256), dim3(512), 0, stream,
                       pfhi, pflo, pahi, palo, sims);            // tile 0 of each chunk
    hipLaunchKernelGGL(bisect_thresh, dim3(B_ROWS), dim3(256), 0, stream,
                       sims, cand, cnt, Tarr);
    hipLaunchKernelGGL(knn_mfma_append, dim3(1536), dim3(1024), 0, stream,
                       qfhi, qflo, pahi, palo, Tarr, cand, cnt); // tiles 1..12
    hipLaunchKernelGGL(knn_final, dim3(B_ROWS), dim3(256), 0, stream,
                       cand, cnt, labels, anchor_label, out);
}